// Round 4
// baseline (176522.791 us; speedup 1.0000x reference)
//
#include <hip/hip_runtime.h>

// Persistent diagonal-pipelined GRU. ALL weights bf16-packed in LDS (122.9 KB:
// Wh z/r/g x3 + Wx1/Wx2 z/r/g, 4 j-rows per block) -> phases read zero weight
// bytes from L2/HBM. f32 accumulate via v_dot2_f32_bf16.
// Activation transport: pair-interleaved layout [kp/2][b][2] (lane's pair =
// two ADJACENT dwords), 32-bit agent-scope atomic loads.
// r1-r3 lesson: big (96-dword) register prefetch arrays ALWAYS spill -- the
// backend pins this kernel at 128 VGPRs regardless of __launch_bounds__
// (FETCH/WRITE ~140/110 GB = scratch round-trips, VGPR_Count stuck at 128).
// THIS ROUND: chunked double-buffered prefetch SIZED TO FIT 128 VGPRs:
// 16-dword buffers (8 k-iters), issue chunk N+1 while consuming chunk N.
// Peak live ~90 regs -> spill-proof even at the 128 cap; 16-32 loads in
// flight vs <=4 in the 25.0ms baseline. amdgpu_waves_per_eu(2,2) declares
// the true occupancy (8 waves/CU) to hand the allocator the 256 budget.
// 256 blocks x 512 threads, 1 block/CU; 2 grid barriers per macro-step.

#ifndef __has_builtin
#define __has_builtin(x) 0
#endif
#if __has_builtin(__builtin_amdgcn_fdot2_f32_bf16)
#define HAS_DOT2 1
typedef __bf16 bf16x2 __attribute__((ext_vector_type(2)));
#else
#define HAS_DOT2 0
#endif

struct GruParams {
  const float* x;            // (32, 512, 128)
  const float* Wx[3][3];     // [layer][gate z,r,g]
  const float* Wh[3][3];
  const float* bias[3][3];
  const float* Wout;         // (128, 1024)
  const float* bout;         // (128)
  unsigned* hP;              // [3][256 kpp][32 b][2] packed bf16 pairs (interleaved)
  unsigned* rhP;             // same layout
  float* hF;                 // [3][1024 j][32 b] f32 (owner-private)
  unsigned* bar;
  float* out;                // (B,S,O)
  float* outHid;             // (B,L,H)
};

// LDS dword map: 15 weight slices x 2048 dwords, Wout 512, scratch 9472 fl
#define WH0z 0
#define WH0r 2048
#define WH0g 4096
#define WH1z 6144
#define WH1r 8192
#define WH1g 10240
#define WH2z 12288
#define WH2r 14336
#define WH2g 16384
#define WX1z 18432
#define WX1r 20480
#define WX1g 22528
#define WX2z 24576
#define WX2r 26624
#define WX2g 28672
#define WOUTO 30720
#define SCRO  31232
#define LDSB ((SCRO + 8 * 1184) * 4)    // 162,816 B <= 160 KiB

extern __shared__ unsigned lds_u[];

__device__ __forceinline__ unsigned loadcu(const unsigned* p_) {
  return __hip_atomic_load(p_, __ATOMIC_RELAXED, __HIP_MEMORY_SCOPE_AGENT);
}
__device__ __forceinline__ void storecu(unsigned* p_, unsigned v) {
  __hip_atomic_store(p_, v, __ATOMIC_RELAXED, __HIP_MEMORY_SCOPE_AGENT);
}

__device__ __forceinline__ unsigned short f2bfu(float f) {   // RNE
  union { float f; unsigned u; } c; c.f = f;
  unsigned r = c.u + 0x7fffu + ((c.u >> 16) & 1u);
  return (unsigned short)(r >> 16);
}
__device__ __forceinline__ unsigned pack2(float f0, float f1) {
  return ((unsigned)f2bfu(f1) << 16) | (unsigned)f2bfu(f0);
}

// acc += dot(bf16x2(a), bf16x2(w)) in f32
__device__ __forceinline__ float d2(float acc, unsigned a, unsigned w) {
#if HAS_DOT2
  return __builtin_amdgcn_fdot2_f32_bf16(__builtin_bit_cast(bf16x2, a),
                                         __builtin_bit_cast(bf16x2, w),
                                         acc, false);
#else
  union { unsigned u; float f; } al, ah, wl, wh;
  al.u = a << 16; ah.u = a & 0xffff0000u;
  wl.u = w << 16; wh.u = w & 0xffff0000u;
  return acc + al.f * wl.f + ah.f * wh.f;
#endif
}
__device__ __forceinline__ void fma4(float& acc, float o0, float o1, float o2,
                                     float o3, const float4 v) {
  acc += o0 * v.x; acc += o1 * v.y; acc += o2 * v.z; acc += o3 * v.w;
}

// Two-level barrier: 16 groups x 16 blocks, 128B-strided lines (r6-proven).
__device__ __forceinline__ void gridbar(unsigned* bar, unsigned phase, int bid) {
  __syncthreads();
  if (threadIdx.x == 0) {
    const int g = bid & 15;
    unsigned* grp   = bar + (g << 5);
    unsigned* root  = bar + 512;
    unsigned* go    = bar + 544;
    unsigned* grpGo = bar + 576 + (g << 5);
    const unsigned tgt = phase << 4;
    unsigned old = __hip_atomic_fetch_add(grp, 1u, __ATOMIC_RELAXED, __HIP_MEMORY_SCOPE_AGENT);
    if (old == tgt - 1u) {
      unsigned r = __hip_atomic_fetch_add(root, 1u, __ATOMIC_RELAXED, __HIP_MEMORY_SCOPE_AGENT);
      if (r == tgt - 1u)
        __hip_atomic_store(go, phase, __ATOMIC_RELAXED, __HIP_MEMORY_SCOPE_AGENT);
      while (__hip_atomic_load(go, __ATOMIC_RELAXED, __HIP_MEMORY_SCOPE_AGENT) < phase)
        __builtin_amdgcn_s_sleep(2);
      __hip_atomic_store(grpGo, phase, __ATOMIC_RELAXED, __HIP_MEMORY_SCOPE_AGENT);
    } else {
      while (__hip_atomic_load(grpGo, __ATOMIC_RELAXED, __HIP_MEMORY_SCOPE_AGENT) < phase)
        __builtin_amdgcn_s_sleep(2);
    }
  }
  __syncthreads();
}

// issue one 8-iter chunk (16 dwords) of agent-scope loads into buf
#define ISSUE8(buf, base, IOFF) do {                                  \
  _Pragma("unroll")                                                   \
  for (int i_ = 0; i_ < 8; ++i_) {                                    \
    buf[2*i_]   = loadcu((base) + ((i_ + (IOFF)) << 7));              \
    buf[2*i_+1] = loadcu((base) + ((i_ + (IOFF)) << 7) + 1);          \
  }                                                                   \
  __builtin_amdgcn_sched_barrier(0);                                  \
} while (0)

#define SW1_HALF(buf, H) do {                                         \
  _Pragma("unroll")                                                   \
  for (int i_ = 0; i_ < 8; ++i_) {                                    \
    const int kp0 = (w << 6) + ((i_ + (H)) << 2) + (ks << 1);         \
    const unsigned a0 = buf[2*i_], a1 = buf[2*i_+1];                  \
    _Pragma("unroll")                                                 \
    for (int jj = 0; jj < 4; ++jj) {                                  \
      const int wo = (jj << 9) + kp0;                                 \
      uint2 wv;                                                       \
      wv = *(const uint2*)(lds_u + WH0z + wo); a0z[jj] = d2(d2(a0z[jj], a0, wv.x), a1, wv.y); \
      wv = *(const uint2*)(lds_u + WH0r + wo); a0r[jj] = d2(d2(a0r[jj], a0, wv.x), a1, wv.y); \
      wv = *(const uint2*)(lds_u + WX1z + wo); a1z[jj] = d2(d2(a1z[jj], a0, wv.x), a1, wv.y); \
      wv = *(const uint2*)(lds_u + WX1r + wo); a1r[jj] = d2(d2(a1r[jj], a0, wv.x), a1, wv.y); \
      wv = *(const uint2*)(lds_u + WX1g + wo); a1g[jj] = d2(d2(a1g[jj], a0, wv.x), a1, wv.y); \
    }                                                                 \
  }                                                                   \
} while (0)

#define SW2_HALF(buf, H) do {                                         \
  _Pragma("unroll")                                                   \
  for (int i_ = 0; i_ < 8; ++i_) {                                    \
    const int kp0 = (w << 6) + ((i_ + (H)) << 2) + (ks << 1);         \
    const unsigned a0 = buf[2*i_], a1 = buf[2*i_+1];                  \
    _Pragma("unroll")                                                 \
    for (int jj = 0; jj < 4; ++jj) {                                  \
      const int wo = (jj << 9) + kp0;                                 \
      uint2 wv;                                                       \
      wv = *(const uint2*)(lds_u + WH1z + wo); a1z[jj] = d2(d2(a1z[jj], a0, wv.x), a1, wv.y); \
      wv = *(const uint2*)(lds_u + WH1r + wo); a1r[jj] = d2(d2(a1r[jj], a0, wv.x), a1, wv.y); \
      wv = *(const uint2*)(lds_u + WX2z + wo); a2z[jj] = d2(d2(a2z[jj], a0, wv.x), a1, wv.y); \
      wv = *(const uint2*)(lds_u + WX2r + wo); a2r[jj] = d2(d2(a2r[jj], a0, wv.x), a1, wv.y); \
      wv = *(const uint2*)(lds_u + WX2g + wo); a2g[jj] = d2(d2(a2g[jj], a0, wv.x), a1, wv.y); \
    }                                                                 \
  }                                                                   \
} while (0)

#define SW3_HALF(buf, H) do {                                         \
  _Pragma("unroll")                                                   \
  for (int i_ = 0; i_ < 8; ++i_) {                                    \
    const int kp0 = (w << 6) + ((i_ + (H)) << 2) + (ks << 1);         \
    const unsigned a0 = buf[2*i_], a1 = buf[2*i_+1];                  \
    _Pragma("unroll")                                                 \
    for (int jj = 0; jj < 4; ++jj) {                                  \
      const int wo = (jj << 9) + kp0;                                 \
      uint2 wv;                                                       \
      wv = *(const uint2*)(lds_u + WH2z + wo); a2z[jj] = d2(d2(a2z[jj], a0, wv.x), a1, wv.y); \
      wv = *(const uint2*)(lds_u + WH2r + wo); a2r[jj] = d2(d2(a2r[jj], a0, wv.x), a1, wv.y); \
    }                                                                 \
    if (bid < 128) {                                                  \
      const uint2 wv = *(const uint2*)(lds_u + WOUTO + kp0);          \
      ah = d2(d2(ah, a0, wv.x), a1, wv.y);                            \
    }                                                                 \
  }                                                                   \
} while (0)

#define CG_HALF(buf, H, WOFF, cc) do {                                \
  _Pragma("unroll")                                                   \
  for (int i_ = 0; i_ < 8; ++i_) {                                    \
    const int kp0 = (w << 6) + ((i_ + (H)) << 2) + (ks << 1);         \
    const unsigned r0 = buf[2*i_], r1 = buf[2*i_+1];                  \
    _Pragma("unroll")                                                 \
    for (int jj = 0; jj < 4; ++jj) {                                  \
      const uint2 wv = *(const uint2*)(lds_u + (WOFF) + (jj << 9) + kp0); \
      cc[jj] = d2(d2(cc[jj], r0, wv.x), r1, wv.y);                    \
    }                                                                 \
  }                                                                   \
} while (0)

__global__ __launch_bounds__(512)
__attribute__((amdgpu_waves_per_eu(2, 2)))
void gruPersist(GruParams p) {
  const int tid  = threadIdx.x;
  const int bid  = blockIdx.x;
  const int w    = tid >> 6;        // wave 0..7
  const int lane = tid & 63;
  const int b    = lane & 31;
  const int ks   = lane >> 5;
  const int jbase = bid << 2;
  float* scratch = (float*)(lds_u + SCRO);
  float* my      = scratch + w * 1184;

  // ---- one-time: convert this block's weight slices f32 -> packed bf16 ----
  for (int d = tid; d < 15 * 2048; d += 512) {
    const int s = d >> 11, rem = d & 2047;
    const int jj = rem >> 9, kp = rem & 511;
    const float* src;
    if (s < 9)       src = p.Wh[s / 3][s % 3];
    else if (s < 12) src = p.Wx[1][s - 9];
    else             src = p.Wx[2][s - 12];
    const size_t base = (size_t)(jbase + jj) * 1024 + (size_t)(kp << 1);
    lds_u[d] = pack2(src[base], src[base + 1]);
  }
  if (bid < 128) {   // Wout row `bid`
    const size_t base = (size_t)bid * 1024 + (size_t)(tid << 1);
    lds_u[WOUTO + tid] = pack2(p.Wout[base], p.Wout[base + 1]);
  }
  __syncthreads();

  unsigned* hP0 = p.hP;            unsigned* hP1 = p.hP + 16384;
  unsigned* hP2 = p.hP + 32768;
  unsigned* rq0 = p.rhP;           unsigned* rq1 = p.rhP + 16384;
  unsigned* rq2 = p.rhP + 32768;

  // interleaved layout: dword(kp,b) at (kp>>1)*64 + (b<<1) + (kp&1)
  const int abase = (w << 11) + (ks << 6) + (b << 1);
  const unsigned* hA0 = hP0 + abase;
  const unsigned* hA1 = hP1 + abase;
  const unsigned* hA2 = hP2 + abase;
  const unsigned* rA0 = rq0 + abase;
  const unsigned* rA1 = rq1 + abase;
  const unsigned* rA2 = rq2 + abase;

  unsigned phase = 0;
  float my_z[3][2], my_gx[3][2];
  #pragma unroll
  for (int l = 0; l < 3; ++l) { my_z[l][0]=my_z[l][1]=my_gx[l][0]=my_gx[l][1]=0.f; }

  for (int m = 0; m < 514; ++m) {
    const bool act0 = (m < 512);
    const bool act1 = (m >= 1 && m <= 512);
    const bool act2 = (m >= 2 && m <= 513);
    const int t0 = m, t1 = m - 1, t2 = m - 2, th = m - 3;

    // ===================== phase 1: all A dots ============================
    float a0z[4]={0,0,0,0}, a0r[4]={0,0,0,0}, a0g[4]={0,0,0,0};
    float a1z[4]={0,0,0,0}, a1r[4]={0,0,0,0}, a1g[4]={0,0,0,0};
    float a2z[4]={0,0,0,0}, a2r[4]={0,0,0,0}, a2g[4]={0,0,0,0};
    float ah = 0.f;

    {
      unsigned bufA[16], bufB[16];
      ISSUE8(bufA, hA0, 0);
      ISSUE8(bufB, hA0, 8);

      if (act0) {   // l0 x-side (K=128), hides bufA/bufB flight
        const float* xb = p.x + ((size_t)b << 16) + ((size_t)t0 << 7);
        #pragma unroll
        for (int i = 0; i < 2; ++i) {
          const int k = (w << 4) + (i << 3) + (ks << 2);
          const float4 xv = *(const float4*)(xb + k);
          #pragma unroll
          for (int jj = 0; jj < 4; ++jj) {
            const size_t row = (size_t)(jbase + jj) * 128 + k;
            fma4(a0z[jj], xv.x,xv.y,xv.z,xv.w, *(const float4*)(p.Wx[0][0] + row));
            fma4(a0r[jj], xv.x,xv.y,xv.z,xv.w, *(const float4*)(p.Wx[0][1] + row));
            fma4(a0g[jj], xv.x,xv.y,xv.z,xv.w, *(const float4*)(p.Wx[0][2] + row));
          }
        }
      }

      SW1_HALF(bufA, 0);
      ISSUE8(bufA, hA1, 0);
      SW1_HALF(bufB, 8);
      ISSUE8(bufB, hA1, 8);

      #pragma unroll
      for (int jj = 0; jj < 4; ++jj) {
        a0z[jj] += __shfl_xor(a0z[jj], 32);
        a0r[jj] += __shfl_xor(a0r[jj], 32);
        a0g[jj] += __shfl_xor(a0g[jj], 32);
        a1g[jj] += __shfl_xor(a1g[jj], 32);
      }
      if (ks == 0) {
        #pragma unroll
        for (int jj = 0; jj < 4; ++jj) {
          my[(0*4+jj)*32 + b] = a0z[jj];
          my[(1*4+jj)*32 + b] = a0r[jj];
          my[(2*4+jj)*32 + b] = a0g[jj];
          my[(5*4+jj)*32 + b] = a1g[jj];
        }
      }

      SW2_HALF(bufA, 0);
      ISSUE8(bufA, hA2, 0);
      SW2_HALF(bufB, 8);
      ISSUE8(bufB, hA2, 8);

      #pragma unroll
      for (int jj = 0; jj < 4; ++jj) {
        a1z[jj] += __shfl_xor(a1z[jj], 32);
        a1r[jj] += __shfl_xor(a1r[jj], 32);
        a2g[jj] += __shfl_xor(a2g[jj], 32);
      }
      if (ks == 0) {
        #pragma unroll
        for (int jj = 0; jj < 4; ++jj) {
          my[(3*4+jj)*32 + b] = a1z[jj];
          my[(4*4+jj)*32 + b] = a1r[jj];
          my[(8*4+jj)*32 + b] = a2g[jj];
        }
      }

      SW3_HALF(bufA, 0);
      SW3_HALF(bufB, 8);

      #pragma unroll
      for (int jj = 0; jj < 4; ++jj) {
        a2z[jj] += __shfl_xor(a2z[jj], 32);
        a2r[jj] += __shfl_xor(a2r[jj], 32);
      }
      ah += __shfl_xor(ah, 32);
      if (ks == 0) {
        #pragma unroll
        for (int jj = 0; jj < 4; ++jj) {
          my[(6*4+jj)*32 + b] = a2z[jj];
          my[(7*4+jj)*32 + b] = a2r[jj];
        }
        my[1152 + b] = ah;
      }
    }

    __syncthreads();
    // epilogue: tid<64 owns a j-PAIR (j0=jbase+2jp, j0+1) x batch bb
    if (tid < 64) {
      const int jp = tid >> 5, bb = tid & 31;
      const int j0 = jbase + (jp << 1);
      #pragma unroll
      for (int l = 0; l < 3; ++l) {
        float rr[2];
        #pragma unroll
        for (int q = 0; q < 2; ++q) {
          const int jj = (jp << 1) + q;
          float sz = 0.f, sr = 0.f, sg = 0.f;
          #pragma unroll
          for (int ww = 0; ww < 8; ++ww) {
            sz += scratch[ww * 1184 + ((l*3+0)*4 + jj)*32 + bb];
            sr += scratch[ww * 1184 + ((l*3+1)*4 + jj)*32 + bb];
            sg += scratch[ww * 1184 + ((l*3+2)*4 + jj)*32 + bb];
          }
          const int j = j0 + q;
          const float zp = sz + p.bias[l][0][j];
          const float rp = sr + p.bias[l][1][j];
          my_gx[l][q] = sg + p.bias[l][2][j];
          my_z[l][q]  = 1.f / (1.f + expf(-zp));
          const float r = 1.f / (1.f + expf(-rp));
          rr[q] = r * p.hF[l * 32768 + j * 32 + bb];
        }
        unsigned* rq = (l == 0) ? rq0 : (l == 1) ? rq1 : rq2;
        storecu(rq + (bid << 6) + (bb << 1) + jp, pack2(rr[0], rr[1]));
      }
    }
    if (m >= 3 && bid < 128 && tid < 32) {
      float s = 0.f;
      #pragma unroll
      for (int ww = 0; ww < 8; ++ww) s += scratch[ww * 1184 + 1152 + tid];
      p.out[((size_t)tid << 16) + ((size_t)th << 7) + bid] = s + p.bout[bid];
    }

    ++phase; gridbar(p.bar, phase, bid);

    // ===================== phase 2: fused C ===============================
    float c0[4]={0,0,0,0}, c1[4]={0,0,0,0}, c2[4]={0,0,0,0};
    {
      unsigned bufA[16], bufB[16], bufC[16];
      ISSUE8(bufA, rA0, 0);
      ISSUE8(bufB, rA0, 8);
      ISSUE8(bufC, rA1, 0);
      CG_HALF(bufA, 0, WH0g, c0);
      ISSUE8(bufA, rA1, 8);
      CG_HALF(bufB, 8, WH0g, c0);
      ISSUE8(bufB, rA2, 0);
      CG_HALF(bufC, 0, WH1g, c1);
      ISSUE8(bufC, rA2, 8);
      CG_HALF(bufA, 8, WH1g, c1);
      CG_HALF(bufB, 0, WH2g, c2);
      CG_HALF(bufC, 8, WH2g, c2);
    }
    #pragma unroll
    for (int jj = 0; jj < 4; ++jj) {
      c0[jj] += __shfl_xor(c0[jj], 32);
      c1[jj] += __shfl_xor(c1[jj], 32);
      c2[jj] += __shfl_xor(c2[jj], 32);
    }
    if (ks == 0) {
      #pragma unroll
      for (int jj = 0; jj < 4; ++jj) {
        my[(0*4+jj)*32 + b] = c0[jj];
        my[(1*4+jj)*32 + b] = c1[jj];
        my[(2*4+jj)*32 + b] = c2[jj];
      }
    }
    __syncthreads();
    if (tid < 64) {
      const int jp = tid >> 5, bb = tid & 31;
      const int j0 = jbase + (jp << 1);
      #pragma unroll
      for (int l = 0; l < 3; ++l) {
        const bool act = (l == 0) ? act0 : (l == 1) ? act1 : act2;
        if (!act) continue;
        const int tl = (l == 0) ? t0 : (l == 1) ? t1 : t2;
        float hb[2];
        #pragma unroll
        for (int q = 0; q < 2; ++q) {
          const int jj = (jp << 1) + q;
          float cv = 0.f;
          #pragma unroll
          for (int ww = 0; ww < 8; ++ww)
            cv += scratch[ww * 1184 + (l*4 + jj)*32 + bb];
          const float g = tanhf(cv + my_gx[l][q]);
          float* hf = p.hF + l * 32768 + (j0 + q) * 32 + bb;
          const float hp = *hf;
          const float hn = my_z[l][q] * hp + (1.f - my_z[l][q]) * g;
          *hf = hn;
          hb[q] = hn;
          if (tl == 511) p.outHid[bb * 3072 + l * 1024 + (j0 + q)] = hn;
        }
        unsigned* hq = (l == 0) ? hP0 : (l == 1) ? hP1 : hP2;
        storecu(hq + (bid << 6) + (bb << 1) + jp, pack2(hb[0], hb[1]));
      }
    }
    ++phase; gridbar(p.bar, phase, bid);
  } // m

  // final head: t=511
  float ah = 0.f;
  if (bid < 128) {
    #pragma unroll 2
    for (int i = 0; i < 16; ++i) {
      const int kp0 = (w << 6) + (i << 2) + (ks << 1);
      const unsigned a0 = loadcu(hA2 + (i << 7));
      const unsigned a1 = loadcu(hA2 + (i << 7) + 1);
      const uint2 wv = *(const uint2*)(lds_u + WOUTO + kp0);
      ah = d2(d2(ah, a0, wv.x), a1, wv.y);
    }
    ah += __shfl_xor(ah, 32);
    if (ks == 0) scratch[w * 1184 + b] = ah;
  }
  __syncthreads();
  if (bid < 128 && tid < 32) {
    float s = 0.f;
    #pragma unroll
    for (int ww = 0; ww < 8; ++ww) s += scratch[ww * 1184 + tid];
    p.out[((size_t)tid << 16) + ((size_t)511 << 7) + bid] = s + p.bout[bid];
  }
}

// Zero hP, rhP, hF, bar (ws poisoned 0xAA before every timed launch).
__global__ void initWs(unsigned* wsd) {
  const int i = blockIdx.x * 1024 + threadIdx.x;
  if (i < 198656) wsd[i] = 0u;
}

extern "C" void kernel_launch(void* const* d_in, const int* in_sizes, int n_in,
                              void* d_out, int out_size, void* d_ws, size_t ws_size,
                              hipStream_t stream)
{
  GruParams P;
  P.x = (const float*)d_in[0];
  P.Wx[0][0] = (const float*)d_in[1];  P.Wh[0][0] = (const float*)d_in[2];
  P.bias[0][0] = (const float*)d_in[3];
  P.Wx[0][1] = (const float*)d_in[4];  P.Wh[0][1] = (const float*)d_in[5];
  P.bias[0][1] = (const float*)d_in[6];
  P.Wx[0][2] = (const float*)d_in[7];  P.Wh[0][2] = (const float*)d_in[8];
  P.bias[0][2] = (const float*)d_in[9];
  for (int l = 1; l < 3; ++l) {
    const size_t off = (size_t)(l - 1) * 1048576;
    const size_t ob  = (size_t)(l - 1) * 1024;
    P.Wx[l][0] = (const float*)d_in[10] + off; P.Wh[l][0] = (const float*)d_in[11] + off;
    P.bias[l][0] = (const float*)d_in[12] + ob;
    P.Wx[l][1] = (const float*)d_in[13] + off; P.Wh[l][1] = (const float*)d_in[14] + off;
    P.bias[l][1] = (const float*)d_in[15] + ob;
    P.Wx[l][2] = (const float*)d_in[16] + off; P.Wh[l][2] = (const float*)d_in[17] + off;
    P.bias[l][2] = (const float*)d_in[18] + ob;
  }
  P.Wout = (const float*)d_in[19];
  P.bout = (const float*)d_in[20];

  char* ws = (char*)d_ws;
  P.hP  = (unsigned*)ws;                 // 3*16384 uints  = 196,608 B
  P.rhP = (unsigned*)(ws + 196608);      // 3*16384 uints  = 196,608 B
  P.hF  = (float*)(ws + 393216);         // 3*32768 f32    = 393,216 B
  P.bar = (unsigned*)(ws + 786432);      // 2048 uints
  P.out = (float*)d_out;
  P.outHid = P.out + 2097152;

  hipFuncSetAttribute(reinterpret_cast<const void*>(gruPersist),
                      hipFuncAttributeMaxDynamicSharedMemorySize, LDSB);

  initWs<<<194, 1024, 0, stream>>>((unsigned*)ws);
  gruPersist<<<256, 512, LDSB, stream>>>(P);
}

// Round 6
// 25462.845 us; speedup vs baseline: 6.9326x; 6.9326x over previous
//
#include <hip/hip_runtime.h>

// Persistent diagonal-pipelined GRU. ALL weights bf16-packed in LDS (122.9 KB:
// Wh z/r/g x3 + Wx1/Wx2 z/r/g, 4 j-rows per block) -> phases read zero weight
// bytes from L2/HBM. f32 accumulate via v_dot2_f32_bf16.
// Transport: EXACT r0 pattern (proven 0.86GB FETCH): [kp][b] layout, 2
// agent-scope dword loads per k-iter inside the sweep, #pragma unroll 2,
// NO batched register arrays, NO sched_barrier. r1-r4 lesson: every
// batched-prefetch variant (any size, any width, any launch bounds) blew up
// to ~140GB FETCH / ~110GB WRITE and 7x regression -- do not restructure
// the load pattern.
// TLP round (r5 resubmit; r5 died to container infra with no profile --
// kernel audited hang-safe: 1 block/CU x 256 blocks means launch success
// implies full co-residency, so gridbar cannot deadlock):
// 1024 threads/block = 16 waves = 4 waves/SIMD (was 2): each wave sweeps
// HALF the k-range (8 iters -> half the latency exposures) and twice as
// many waves overlap each exposure. 16-wave partials fold pairwise (w,w+8)
// into 8 scratch slots (one extra __syncthreads per phase; f32 adds,
// deterministic). Grid/barrier unchanged: 256 blocks, 2 grid barriers/step.

#ifndef __has_builtin
#define __has_builtin(x) 0
#endif
#if __has_builtin(__builtin_amdgcn_fdot2_f32_bf16)
#define HAS_DOT2 1
typedef __bf16 bf16x2 __attribute__((ext_vector_type(2)));
#else
#define HAS_DOT2 0
#endif

struct GruParams {
  const float* x;            // (32, 512, 128)
  const float* Wx[3][3];     // [layer][gate z,r,g]
  const float* Wh[3][3];
  const float* bias[3][3];
  const float* Wout;         // (128, 1024)
  const float* bout;         // (128)
  unsigned* hP;              // [3][512 kp][32 b] packed bf16 pairs
  unsigned* rhP;             // same layout
  float* hF;                 // [3][1024 j][32 b] f32 (owner-private)
  unsigned* bar;
  float* out;                // (B,S,O)
  float* outHid;             // (B,L,H)
};

// LDS dword map: 15 weight slices x 2048 dwords, Wout 512, scratch 9472 fl
#define WH0z 0
#define WH0r 2048
#define WH0g 4096
#define WH1z 6144
#define WH1r 8192
#define WH1g 10240
#define WH2z 12288
#define WH2r 14336
#define WH2g 16384
#define WX1z 18432
#define WX1r 20480
#define WX1g 22528
#define WX2z 24576
#define WX2r 26624
#define WX2g 28672
#define WOUTO 30720
#define SCRO  31232
#define LDSB ((SCRO + 8 * 1184) * 4)    // 162,816 B <= 160 KiB

extern __shared__ unsigned lds_u[];

__device__ __forceinline__ unsigned loadcu(const unsigned* p_) {
  return __hip_atomic_load(p_, __ATOMIC_RELAXED, __HIP_MEMORY_SCOPE_AGENT);
}
__device__ __forceinline__ void storecu(unsigned* p_, unsigned v) {
  __hip_atomic_store(p_, v, __ATOMIC_RELAXED, __HIP_MEMORY_SCOPE_AGENT);
}

__device__ __forceinline__ unsigned short f2bfu(float f) {   // RNE
  union { float f; unsigned u; } c; c.f = f;
  unsigned r = c.u + 0x7fffu + ((c.u >> 16) & 1u);
  return (unsigned short)(r >> 16);
}
__device__ __forceinline__ unsigned pack2(float f0, float f1) {
  return ((unsigned)f2bfu(f1) << 16) | (unsigned)f2bfu(f0);
}

// acc += dot(bf16x2(a), bf16x2(w)) in f32
__device__ __forceinline__ float d2(float acc, unsigned a, unsigned w) {
#if HAS_DOT2
  return __builtin_amdgcn_fdot2_f32_bf16(__builtin_bit_cast(bf16x2, a),
                                         __builtin_bit_cast(bf16x2, w),
                                         acc, false);
#else
  union { unsigned u; float f; } al, ah, wl, wh;
  al.u = a << 16; ah.u = a & 0xffff0000u;
  wl.u = w << 16; wh.u = w & 0xffff0000u;
  return acc + al.f * wl.f + ah.f * wh.f;
#endif
}
__device__ __forceinline__ void fma4(float& acc, float o0, float o1, float o2,
                                     float o3, const float4 v) {
  acc += o0 * v.x; acc += o1 * v.y; acc += o2 * v.z; acc += o3 * v.w;
}

// Two-level barrier: 16 groups x 16 blocks, 128B-strided lines (r6-proven).
__device__ __forceinline__ void gridbar(unsigned* bar, unsigned phase, int bid) {
  __syncthreads();
  if (threadIdx.x == 0) {
    const int g = bid & 15;
    unsigned* grp   = bar + (g << 5);
    unsigned* root  = bar + 512;
    unsigned* go    = bar + 544;
    unsigned* grpGo = bar + 576 + (g << 5);
    const unsigned tgt = phase << 4;
    unsigned old = __hip_atomic_fetch_add(grp, 1u, __ATOMIC_RELAXED, __HIP_MEMORY_SCOPE_AGENT);
    if (old == tgt - 1u) {
      unsigned r = __hip_atomic_fetch_add(root, 1u, __ATOMIC_RELAXED, __HIP_MEMORY_SCOPE_AGENT);
      if (r == tgt - 1u)
        __hip_atomic_store(go, phase, __ATOMIC_RELAXED, __HIP_MEMORY_SCOPE_AGENT);
      while (__hip_atomic_load(go, __ATOMIC_RELAXED, __HIP_MEMORY_SCOPE_AGENT) < phase)
        __builtin_amdgcn_s_sleep(2);
      __hip_atomic_store(grpGo, phase, __ATOMIC_RELAXED, __HIP_MEMORY_SCOPE_AGENT);
    } else {
      while (__hip_atomic_load(grpGo, __ATOMIC_RELAXED, __HIP_MEMORY_SCOPE_AGENT) < phase)
        __builtin_amdgcn_s_sleep(2);
    }
  }
  __syncthreads();
}

__global__ __launch_bounds__(1024) void gruPersist(GruParams p) {
  const int tid  = threadIdx.x;
  const int bid  = blockIdx.x;
  const int w    = tid >> 6;        // wave 0..15
  const int lane = tid & 63;
  const int b    = lane & 31;
  const int ks   = lane >> 5;
  const int jbase = bid << 2;
  float* scratch = (float*)(lds_u + SCRO);
  float* slot    = scratch + (w & 7) * 1184;   // waves w and w+8 share a slot

  // ---- one-time: convert this block's weight slices f32 -> packed bf16 ----
  for (int d = tid; d < 15 * 2048; d += 1024) {
    const int s = d >> 11, rem = d & 2047;
    const int jj = rem >> 9, kp = rem & 511;
    const float* src;
    if (s < 9)       src = p.Wh[s / 3][s % 3];
    else if (s < 12) src = p.Wx[1][s - 9];
    else             src = p.Wx[2][s - 12];
    const size_t base = (size_t)(jbase + jj) * 1024 + (size_t)(kp << 1);
    lds_u[d] = pack2(src[base], src[base + 1]);
  }
  if (bid < 128 && tid < 512) {   // Wout row `bid`
    const size_t base = (size_t)bid * 1024 + (size_t)(tid << 1);
    lds_u[WOUTO + tid] = pack2(p.Wout[base], p.Wout[base + 1]);
  }
  __syncthreads();

  unsigned* hP0 = p.hP;            unsigned* hP1 = p.hP + 16384;
  unsigned* hP2 = p.hP + 32768;
  unsigned* rq0 = p.rhP;           unsigned* rq1 = p.rhP + 16384;
  unsigned* rq2 = p.rhP + 32768;

  unsigned phase = 0;
  float my_z[3][2], my_gx[3][2];
  #pragma unroll
  for (int l = 0; l < 3; ++l) { my_z[l][0]=my_z[l][1]=my_gx[l][0]=my_gx[l][1]=0.f; }

  for (int m = 0; m < 514; ++m) {
    const bool act0 = (m < 512);
    const bool act1 = (m >= 1 && m <= 512);
    const bool act2 = (m >= 2 && m <= 513);
    const int t0 = m, t1 = m - 1, t2 = m - 2, th = m - 3;

    // ===================== phase 1: all A dots ============================
    float a0z[4]={0,0,0,0}, a0r[4]={0,0,0,0}, a0g[4]={0,0,0,0};
    float a1z[4]={0,0,0,0}, a1r[4]={0,0,0,0}, a1g[4]={0,0,0,0};
    float a2z[4]={0,0,0,0}, a2r[4]={0,0,0,0}, a2g[4]={0,0,0,0};
    float ah = 0.f;

    if (act0) {   // l0 x-side (K=128): lane (w,ks) owns k-group [8w+4ks, +4)
      const float* xb = p.x + ((size_t)b << 16) + ((size_t)t0 << 7);
      const int k = (w << 3) + (ks << 2);
      const float4 xv = *(const float4*)(xb + k);
      #pragma unroll
      for (int jj = 0; jj < 4; ++jj) {
        const size_t row = (size_t)(jbase + jj) * 128 + k;
        fma4(a0z[jj], xv.x,xv.y,xv.z,xv.w, *(const float4*)(p.Wx[0][0] + row));
        fma4(a0r[jj], xv.x,xv.y,xv.z,xv.w, *(const float4*)(p.Wx[0][1] + row));
        fma4(a0g[jj], xv.x,xv.y,xv.z,xv.w, *(const float4*)(p.Wx[0][2] + row));
      }
    }

    // sweep1 over h0: l0 z/r (Wh0) + l1 z/r/g (Wx1)  -- wave w owns 8 k-iters
    #pragma unroll 2
    for (int i = 0; i < 8; ++i) {
      const int kp0 = (w << 5) + (i << 2) + (ks << 1);
      const unsigned a0 = loadcu(hP0 + kp0 * 32 + b);
      const unsigned a1 = loadcu(hP0 + (kp0 + 1) * 32 + b);
      #pragma unroll
      for (int jj = 0; jj < 4; ++jj) {
        const int wo = (jj << 9) + kp0;
        uint2 wv;
        wv = *(const uint2*)(lds_u + WH0z + wo); a0z[jj] = d2(d2(a0z[jj], a0, wv.x), a1, wv.y);
        wv = *(const uint2*)(lds_u + WH0r + wo); a0r[jj] = d2(d2(a0r[jj], a0, wv.x), a1, wv.y);
        wv = *(const uint2*)(lds_u + WX1z + wo); a1z[jj] = d2(d2(a1z[jj], a0, wv.x), a1, wv.y);
        wv = *(const uint2*)(lds_u + WX1r + wo); a1r[jj] = d2(d2(a1r[jj], a0, wv.x), a1, wv.y);
        wv = *(const uint2*)(lds_u + WX1g + wo); a1g[jj] = d2(d2(a1g[jj], a0, wv.x), a1, wv.y);
      }
    }

    // sweep2 over h1: l1 z/r (Wh1) + l2 z/r/g (Wx2)
    #pragma unroll 2
    for (int i = 0; i < 8; ++i) {
      const int kp0 = (w << 5) + (i << 2) + (ks << 1);
      const unsigned a0 = loadcu(hP1 + kp0 * 32 + b);
      const unsigned a1 = loadcu(hP1 + (kp0 + 1) * 32 + b);
      #pragma unroll
      for (int jj = 0; jj < 4; ++jj) {
        const int wo = (jj << 9) + kp0;
        uint2 wv;
        wv = *(const uint2*)(lds_u + WH1z + wo); a1z[jj] = d2(d2(a1z[jj], a0, wv.x), a1, wv.y);
        wv = *(const uint2*)(lds_u + WH1r + wo); a1r[jj] = d2(d2(a1r[jj], a0, wv.x), a1, wv.y);
        wv = *(const uint2*)(lds_u + WX2z + wo); a2z[jj] = d2(d2(a2z[jj], a0, wv.x), a1, wv.y);
        wv = *(const uint2*)(lds_u + WX2r + wo); a2r[jj] = d2(d2(a2r[jj], a0, wv.x), a1, wv.y);
        wv = *(const uint2*)(lds_u + WX2g + wo); a2g[jj] = d2(d2(a2g[jj], a0, wv.x), a1, wv.y);
      }
    }

    // sweep3 over h2: l2 z/r (Wh2) + head (bid<128: Wout row bid)
    #pragma unroll 2
    for (int i = 0; i < 8; ++i) {
      const int kp0 = (w << 5) + (i << 2) + (ks << 1);
      const unsigned a0 = loadcu(hP2 + kp0 * 32 + b);
      const unsigned a1 = loadcu(hP2 + (kp0 + 1) * 32 + b);
      #pragma unroll
      for (int jj = 0; jj < 4; ++jj) {
        const int wo = (jj << 9) + kp0;
        uint2 wv;
        wv = *(const uint2*)(lds_u + WH2z + wo); a2z[jj] = d2(d2(a2z[jj], a0, wv.x), a1, wv.y);
        wv = *(const uint2*)(lds_u + WH2r + wo); a2r[jj] = d2(d2(a2r[jj], a0, wv.x), a1, wv.y);
      }
      if (bid < 128) {
        const uint2 wv = *(const uint2*)(lds_u + WOUTO + kp0);
        ah = d2(d2(ah, a0, wv.x), a1, wv.y);
      }
    }

    // combine ks halves in-wave
    #pragma unroll
    for (int jj = 0; jj < 4; ++jj) {
      a0z[jj] += __shfl_xor(a0z[jj], 32);
      a0r[jj] += __shfl_xor(a0r[jj], 32);
      a0g[jj] += __shfl_xor(a0g[jj], 32);
      a1z[jj] += __shfl_xor(a1z[jj], 32);
      a1r[jj] += __shfl_xor(a1r[jj], 32);
      a1g[jj] += __shfl_xor(a1g[jj], 32);
      a2z[jj] += __shfl_xor(a2z[jj], 32);
      a2r[jj] += __shfl_xor(a2r[jj], 32);
      a2g[jj] += __shfl_xor(a2g[jj], 32);
    }
    ah += __shfl_xor(ah, 32);

    // two-stage fold: upper waves deposit, lower waves add
    if (w >= 8 && ks == 0) {
      #pragma unroll
      for (int jj = 0; jj < 4; ++jj) {
        slot[(0*4+jj)*32 + b] = a0z[jj];
        slot[(1*4+jj)*32 + b] = a0r[jj];
        slot[(2*4+jj)*32 + b] = a0g[jj];
        slot[(3*4+jj)*32 + b] = a1z[jj];
        slot[(4*4+jj)*32 + b] = a1r[jj];
        slot[(5*4+jj)*32 + b] = a1g[jj];
        slot[(6*4+jj)*32 + b] = a2z[jj];
        slot[(7*4+jj)*32 + b] = a2r[jj];
        slot[(8*4+jj)*32 + b] = a2g[jj];
      }
      slot[1152 + b] = ah;
    }
    __syncthreads();
    if (w < 8 && ks == 0) {
      #pragma unroll
      for (int jj = 0; jj < 4; ++jj) {
        slot[(0*4+jj)*32 + b] += a0z[jj];
        slot[(1*4+jj)*32 + b] += a0r[jj];
        slot[(2*4+jj)*32 + b] += a0g[jj];
        slot[(3*4+jj)*32 + b] += a1z[jj];
        slot[(4*4+jj)*32 + b] += a1r[jj];
        slot[(5*4+jj)*32 + b] += a1g[jj];
        slot[(6*4+jj)*32 + b] += a2z[jj];
        slot[(7*4+jj)*32 + b] += a2r[jj];
        slot[(8*4+jj)*32 + b] += a2g[jj];
      }
      slot[1152 + b] += ah;
    }
    __syncthreads();

    // epilogue: tid<64 owns a j-PAIR (j0=jbase+2jp, j0+1) x batch bb
    if (tid < 64) {
      const int jp = tid >> 5, bb = tid & 31;
      const int j0 = jbase + (jp << 1);
      #pragma unroll
      for (int l = 0; l < 3; ++l) {
        float rr[2];
        #pragma unroll
        for (int q = 0; q < 2; ++q) {
          const int jj = (jp << 1) + q;
          float sz = 0.f, sr = 0.f, sg = 0.f;
          #pragma unroll
          for (int ww = 0; ww < 8; ++ww) {
            sz += scratch[ww * 1184 + ((l*3+0)*4 + jj)*32 + bb];
            sr += scratch[ww * 1184 + ((l*3+1)*4 + jj)*32 + bb];
            sg += scratch[ww * 1184 + ((l*3+2)*4 + jj)*32 + bb];
          }
          const int j = j0 + q;
          const float zp = sz + p.bias[l][0][j];
          const float rp = sr + p.bias[l][1][j];
          my_gx[l][q] = sg + p.bias[l][2][j];
          my_z[l][q]  = 1.f / (1.f + expf(-zp));
          const float r = 1.f / (1.f + expf(-rp));
          rr[q] = r * p.hF[l * 32768 + j * 32 + bb];
        }
        unsigned* rq = (l == 0) ? rq0 : (l == 1) ? rq1 : rq2;
        storecu(rq + ((bid << 1) + jp) * 32 + bb, pack2(rr[0], rr[1]));
      }
    }
    if (m >= 3 && bid < 128 && tid < 32) {
      float s = 0.f;
      #pragma unroll
      for (int ww = 0; ww < 8; ++ww) s += scratch[ww * 1184 + 1152 + tid];
      p.out[((size_t)tid << 16) + ((size_t)th << 7) + bid] = s + p.bout[bid];
    }

    ++phase; gridbar(p.bar, phase, bid);

    // ===================== phase 2: fused C ===============================
    float c0[4]={0,0,0,0}, c1[4]={0,0,0,0}, c2[4]={0,0,0,0};
    #pragma unroll 2
    for (int i = 0; i < 8; ++i) {
      const int kp0 = (w << 5) + (i << 2) + (ks << 1);
      const unsigned r00 = loadcu(rq0 + kp0 * 32 + b);
      const unsigned r01 = loadcu(rq0 + (kp0 + 1) * 32 + b);
      const unsigned r10 = loadcu(rq1 + kp0 * 32 + b);
      const unsigned r11 = loadcu(rq1 + (kp0 + 1) * 32 + b);
      const unsigned r20 = loadcu(rq2 + kp0 * 32 + b);
      const unsigned r21 = loadcu(rq2 + (kp0 + 1) * 32 + b);
      #pragma unroll
      for (int jj = 0; jj < 4; ++jj) {
        const int wo = (jj << 9) + kp0;
        uint2 wv;
        wv = *(const uint2*)(lds_u + WH0g + wo); c0[jj] = d2(d2(c0[jj], r00, wv.x), r01, wv.y);
        wv = *(const uint2*)(lds_u + WH1g + wo); c1[jj] = d2(d2(c1[jj], r10, wv.x), r11, wv.y);
        wv = *(const uint2*)(lds_u + WH2g + wo); c2[jj] = d2(d2(c2[jj], r20, wv.x), r21, wv.y);
      }
    }
    #pragma unroll
    for (int jj = 0; jj < 4; ++jj) {
      c0[jj] += __shfl_xor(c0[jj], 32);
      c1[jj] += __shfl_xor(c1[jj], 32);
      c2[jj] += __shfl_xor(c2[jj], 32);
    }
    if (w >= 8 && ks == 0) {
      #pragma unroll
      for (int jj = 0; jj < 4; ++jj) {
        slot[(0*4+jj)*32 + b] = c0[jj];
        slot[(1*4+jj)*32 + b] = c1[jj];
        slot[(2*4+jj)*32 + b] = c2[jj];
      }
    }
    __syncthreads();
    if (w < 8 && ks == 0) {
      #pragma unroll
      for (int jj = 0; jj < 4; ++jj) {
        slot[(0*4+jj)*32 + b] += c0[jj];
        slot[(1*4+jj)*32 + b] += c1[jj];
        slot[(2*4+jj)*32 + b] += c2[jj];
      }
    }
    __syncthreads();
    if (tid < 64) {
      const int jp = tid >> 5, bb = tid & 31;
      const int j0 = jbase + (jp << 1);
      #pragma unroll
      for (int l = 0; l < 3; ++l) {
        const bool act = (l == 0) ? act0 : (l == 1) ? act1 : act2;
        if (!act) continue;
        const int tl = (l == 0) ? t0 : (l == 1) ? t1 : t2;
        float hb[2];
        #pragma unroll
        for (int q = 0; q < 2; ++q) {
          const int jj = (jp << 1) + q;
          float cv = 0.f;
          #pragma unroll
          for (int ww = 0; ww < 8; ++ww)
            cv += scratch[ww * 1184 + (l*4 + jj)*32 + bb];
          const float g = tanhf(cv + my_gx[l][q]);
          float* hf = p.hF + l * 32768 + (j0 + q) * 32 + bb;
          const float hp = *hf;
          const float hn = my_z[l][q] * hp + (1.f - my_z[l][q]) * g;
          *hf = hn;
          hb[q] = hn;
          if (tl == 511) p.outHid[bb * 3072 + l * 1024 + (j0 + q)] = hn;
        }
        unsigned* hq = (l == 0) ? hP0 : (l == 1) ? hP1 : hP2;
        storecu(hq + ((bid << 1) + jp) * 32 + bb, pack2(hb[0], hb[1]));
      }
    }
    ++phase; gridbar(p.bar, phase, bid);
  } // m

  // final head: t=511 (16 wave-partials, stride-64 scratch slots)
  float ah = 0.f;
  if (bid < 128) {
    #pragma unroll 2
    for (int i = 0; i < 8; ++i) {
      const int kp0 = (w << 5) + (i << 2) + (ks << 1);
      const unsigned a0 = loadcu(hP2 + kp0 * 32 + b);
      const unsigned a1 = loadcu(hP2 + (kp0 + 1) * 32 + b);
      const uint2 wv = *(const uint2*)(lds_u + WOUTO + kp0);
      ah = d2(d2(ah, a0, wv.x), a1, wv.y);
    }
    ah += __shfl_xor(ah, 32);
    if (ks == 0) scratch[w * 64 + b] = ah;
  }
  __syncthreads();
  if (bid < 128 && tid < 32) {
    float s = 0.f;
    #pragma unroll
    for (int ww = 0; ww < 16; ++ww) s += scratch[ww * 64 + tid];
    p.out[((size_t)tid << 16) + ((size_t)511 << 7) + bid] = s + p.bout[bid];
  }
}

// Zero hP, rhP, hF, bar (ws poisoned 0xAA before every timed launch).
__global__ void initWs(unsigned* wsd) {
  const int i = blockIdx.x * 1024 + threadIdx.x;
  if (i < 198656) wsd[i] = 0u;
}

extern "C" void kernel_launch(void* const* d_in, const int* in_sizes, int n_in,
                              void* d_out, int out_size, void* d_ws, size_t ws_size,
                              hipStream_t stream)
{
  GruParams P;
  P.x = (const float*)d_in[0];
  P.Wx[0][0] = (const float*)d_in[1];  P.Wh[0][0] = (const float*)d_in[2];
  P.bias[0][0] = (const float*)d_in[3];
  P.Wx[0][1] = (const float*)d_in[4];  P.Wh[0][1] = (const float*)d_in[5];
  P.bias[0][1] = (const float*)d_in[6];
  P.Wx[0][2] = (const float*)d_in[7];  P.Wh[0][2] = (const float*)d_in[8];
  P.bias[0][2] = (const float*)d_in[9];
  for (int l = 1; l < 3; ++l) {
    const size_t off = (size_t)(l - 1) * 1048576;
    const size_t ob  = (size_t)(l - 1) * 1024;
    P.Wx[l][0] = (const float*)d_in[10] + off; P.Wh[l][0] = (const float*)d_in[11] + off;
    P.bias[l][0] = (const float*)d_in[12] + ob;
    P.Wx[l][1] = (const float*)d_in[13] + off; P.Wh[l][1] = (const float*)d_in[14] + off;
    P.bias[l][1] = (const float*)d_in[15] + ob;
    P.Wx[l][2] = (const float*)d_in[16] + off; P.Wh[l][2] = (const float*)d_in[17] + off;
    P.bias[l][2] = (const float*)d_in[18] + ob;
  }
  P.Wout = (const float*)d_in[19];
  P.bout = (const float*)d_in[20];

  char* ws = (char*)d_ws;
  P.hP  = (unsigned*)ws;                 // 3*16384 uints  = 196,608 B
  P.rhP = (unsigned*)(ws + 196608);      // 3*16384 uints  = 196,608 B
  P.hF  = (float*)(ws + 393216);         // 3*32768 f32    = 393,216 B
  P.bar = (unsigned*)(ws + 786432);      // 2048 uints
  P.out = (float*)d_out;
  P.outHid = P.out + 2097152;

  hipFuncSetAttribute(reinterpret_cast<const void*>(gruPersist),
                      hipFuncAttributeMaxDynamicSharedMemorySize, LDSB);

  initWs<<<194, 1024, 0, stream>>>((unsigned*)ws);
  gruPersist<<<256, 1024, LDSB, stream>>>(P);
}

// Round 7
// 18602.383 us; speedup vs baseline: 9.4893x; 1.3688x over previous
//
#include <hip/hip_runtime.h>

// Persistent diagonal-pipelined GRU. ALL weights bf16-packed in LDS (122.9 KB)
// -> phases read zero weight bytes from L2/HBM. f32 acc via v_dot2_f32_bf16.
// Transport: r0-proven pattern ([kp][b] layout, loads consumed in-iteration,
// no batched register arrays -- r1-r4: those always spill/blow up traffic).
// r6 lesson: duration is INVARIANT to waves/SIMD (2 vs 4 waves both 25ms,
// VALUBusy pinned 25%) -> bottleneck is CU-level: LDS issue rate, correlated
// MALL line-storms, serial 1-wave epilogue. THIS ROUND attacks those three:
//  - ds_read_b128 weight reads (uint4 = 4 kp/instr): halves LDS instr count.
//  - per-CU decorrelation: wave->slice map rotated by bid ((wPhys+bid)&15)
//    and iter order ((i+bid)&3) so the 256 CUs don't storm the same MALL
//    lines simultaneously. Pure reassociation of f32 partial sums.
//  - epilogue on 192 threads (3 waves, l = wave, wave-uniform) vs 64.
// 256 blocks x 1024 threads (16 waves), 1 block/CU; 2 grid barriers/step.

#ifndef __has_builtin
#define __has_builtin(x) 0
#endif
#if __has_builtin(__builtin_amdgcn_fdot2_f32_bf16)
#define HAS_DOT2 1
typedef __bf16 bf16x2 __attribute__((ext_vector_type(2)));
#else
#define HAS_DOT2 0
#endif

struct GruParams {
  const float* x;            // (32, 512, 128)
  const float* Wx[3][3];     // [layer][gate z,r,g]
  const float* Wh[3][3];
  const float* bias[3][3];
  const float* Wout;         // (128, 1024)
  const float* bout;         // (128)
  unsigned* hP;              // [3][512 kp][32 b] packed bf16 pairs
  unsigned* rhP;             // same layout
  float* hF;                 // [3][1024 j][32 b] f32 (owner-private)
  unsigned* bar;
  float* out;                // (B,S,O)
  float* outHid;             // (B,L,H)
};

// LDS dword map: 15 weight slices x 2048 dwords, Wout 512, scratch 9472 fl
#define WH0z 0
#define WH0r 2048
#define WH0g 4096
#define WH1z 6144
#define WH1r 8192
#define WH1g 10240
#define WH2z 12288
#define WH2r 14336
#define WH2g 16384
#define WX1z 18432
#define WX1r 20480
#define WX1g 22528
#define WX2z 24576
#define WX2r 26624
#define WX2g 28672
#define WOUTO 30720
#define SCRO  31232
#define LDSB ((SCRO + 8 * 1184) * 4)    // 162,816 B <= 160 KiB

extern __shared__ unsigned lds_u[];

__device__ __forceinline__ unsigned loadcu(const unsigned* p_) {
  return __hip_atomic_load(p_, __ATOMIC_RELAXED, __HIP_MEMORY_SCOPE_AGENT);
}
__device__ __forceinline__ void storecu(unsigned* p_, unsigned v) {
  __hip_atomic_store(p_, v, __ATOMIC_RELAXED, __HIP_MEMORY_SCOPE_AGENT);
}

__device__ __forceinline__ unsigned short f2bfu(float f) {   // RNE
  union { float f; unsigned u; } c; c.f = f;
  unsigned r = c.u + 0x7fffu + ((c.u >> 16) & 1u);
  return (unsigned short)(r >> 16);
}
__device__ __forceinline__ unsigned pack2(float f0, float f1) {
  return ((unsigned)f2bfu(f1) << 16) | (unsigned)f2bfu(f0);
}

// acc += dot(bf16x2(a), bf16x2(w)) in f32
__device__ __forceinline__ float d2(float acc, unsigned a, unsigned w) {
#if HAS_DOT2
  return __builtin_amdgcn_fdot2_f32_bf16(__builtin_bit_cast(bf16x2, a),
                                         __builtin_bit_cast(bf16x2, w),
                                         acc, false);
#else
  union { unsigned u; float f; } al, ah, wl, wh;
  al.u = a << 16; ah.u = a & 0xffff0000u;
  wl.u = w << 16; wh.u = w & 0xffff0000u;
  return acc + al.f * wl.f + ah.f * wh.f;
#endif
}
// acc += dot over 4 packed pairs (one uint4 weight read)
__device__ __forceinline__ float d8(float acc, unsigned a0, unsigned a1,
                                    unsigned a2, unsigned a3, const uint4 wv) {
  return d2(d2(d2(d2(acc, a0, wv.x), a1, wv.y), a2, wv.z), a3, wv.w);
}
__device__ __forceinline__ void fma4(float& acc, float o0, float o1, float o2,
                                     float o3, const float4 v) {
  acc += o0 * v.x; acc += o1 * v.y; acc += o2 * v.z; acc += o3 * v.w;
}

// Two-level barrier: 16 groups x 16 blocks, 128B-strided lines (r6-proven).
__device__ __forceinline__ void gridbar(unsigned* bar, unsigned phase, int bid) {
  __syncthreads();
  if (threadIdx.x == 0) {
    const int g = bid & 15;
    unsigned* grp   = bar + (g << 5);
    unsigned* root  = bar + 512;
    unsigned* go    = bar + 544;
    unsigned* grpGo = bar + 576 + (g << 5);
    const unsigned tgt = phase << 4;
    unsigned old = __hip_atomic_fetch_add(grp, 1u, __ATOMIC_RELAXED, __HIP_MEMORY_SCOPE_AGENT);
    if (old == tgt - 1u) {
      unsigned r = __hip_atomic_fetch_add(root, 1u, __ATOMIC_RELAXED, __HIP_MEMORY_SCOPE_AGENT);
      if (r == tgt - 1u)
        __hip_atomic_store(go, phase, __ATOMIC_RELAXED, __HIP_MEMORY_SCOPE_AGENT);
      while (__hip_atomic_load(go, __ATOMIC_RELAXED, __HIP_MEMORY_SCOPE_AGENT) < phase)
        __builtin_amdgcn_s_sleep(2);
      __hip_atomic_store(grpGo, phase, __ATOMIC_RELAXED, __HIP_MEMORY_SCOPE_AGENT);
    } else {
      while (__hip_atomic_load(grpGo, __ATOMIC_RELAXED, __HIP_MEMORY_SCOPE_AGENT) < phase)
        __builtin_amdgcn_s_sleep(2);
    }
  }
  __syncthreads();
}

__global__ __launch_bounds__(1024) void gruPersist(GruParams p) {
  const int tid   = threadIdx.x;
  const int bid   = blockIdx.x;
  const int wPhys = tid >> 6;              // physical wave 0..15
  const int w     = (wPhys + bid) & 15;    // rotated kp-slice assignment
  const int lane  = tid & 63;
  const int b     = lane & 31;
  const int ks    = lane >> 5;
  const int jbase = bid << 2;
  float* scratch = (float*)(lds_u + SCRO);
  float* slot    = scratch + (wPhys & 7) * 1184;  // waves wPhys, wPhys+8 pair

  // ---- one-time: convert this block's weight slices f32 -> packed bf16 ----
  for (int d = tid; d < 15 * 2048; d += 1024) {
    const int s = d >> 11, rem = d & 2047;
    const int jj = rem >> 9, kp = rem & 511;
    const float* src;
    if (s < 9)       src = p.Wh[s / 3][s % 3];
    else if (s < 12) src = p.Wx[1][s - 9];
    else             src = p.Wx[2][s - 12];
    const size_t base = (size_t)(jbase + jj) * 1024 + (size_t)(kp << 1);
    lds_u[d] = pack2(src[base], src[base + 1]);
  }
  if (bid < 128 && tid < 512) {   // Wout row `bid`
    const size_t base = (size_t)bid * 1024 + (size_t)(tid << 1);
    lds_u[WOUTO + tid] = pack2(p.Wout[base], p.Wout[base + 1]);
  }
  __syncthreads();

  unsigned* hP0 = p.hP;            unsigned* hP1 = p.hP + 16384;
  unsigned* hP2 = p.hP + 32768;
  unsigned* rq0 = p.rhP;           unsigned* rq1 = p.rhP + 16384;
  unsigned* rq2 = p.rhP + 32768;

  unsigned phase = 0;
  float myZ[2], myGx[2];           // per-thread gate state (l = wave layer)
  myZ[0] = myZ[1] = myGx[0] = myGx[1] = 0.f;

  for (int m = 0; m < 514; ++m) {
    const bool act0 = (m < 512);
    const bool act1 = (m >= 1 && m <= 512);
    const bool act2 = (m >= 2 && m <= 513);
    const int t0 = m, t1 = m - 1, t2 = m - 2, th = m - 3;

    // ===================== phase 1: all A dots ============================
    float a0z[4]={0,0,0,0}, a0r[4]={0,0,0,0}, a0g[4]={0,0,0,0};
    float a1z[4]={0,0,0,0}, a1r[4]={0,0,0,0}, a1g[4]={0,0,0,0};
    float a2z[4]={0,0,0,0}, a2r[4]={0,0,0,0}, a2g[4]={0,0,0,0};
    float ah = 0.f;

    if (act0) {   // l0 x-side (K=128): lane (w,ks) owns k-group [8w+4ks, +4)
      const float* xb = p.x + ((size_t)b << 16) + ((size_t)t0 << 7);
      const int k = (w << 3) + (ks << 2);
      const float4 xv = *(const float4*)(xb + k);
      #pragma unroll
      for (int jj = 0; jj < 4; ++jj) {
        const size_t row = (size_t)(jbase + jj) * 128 + k;
        fma4(a0z[jj], xv.x,xv.y,xv.z,xv.w, *(const float4*)(p.Wx[0][0] + row));
        fma4(a0r[jj], xv.x,xv.y,xv.z,xv.w, *(const float4*)(p.Wx[0][1] + row));
        fma4(a0g[jj], xv.x,xv.y,xv.z,xv.w, *(const float4*)(p.Wx[0][2] + row));
      }
    }

    // sweep1 over h0: l0 z/r (Wh0) + l1 z/r/g (Wx1); wave covers 32 kp
    #pragma unroll 2
    for (int i = 0; i < 4; ++i) {
      const int ii  = (i + bid) & 3;
      const int kp0 = (w << 5) + (ii << 3) + (ks << 2);
      const unsigned a0 = loadcu(hP0 + (kp0 + 0) * 32 + b);
      const unsigned a1 = loadcu(hP0 + (kp0 + 1) * 32 + b);
      const unsigned a2 = loadcu(hP0 + (kp0 + 2) * 32 + b);
      const unsigned a3 = loadcu(hP0 + (kp0 + 3) * 32 + b);
      #pragma unroll
      for (int jj = 0; jj < 4; ++jj) {
        const int wo = (jj << 9) + kp0;
        a0z[jj] = d8(a0z[jj], a0,a1,a2,a3, *(const uint4*)(lds_u + WH0z + wo));
        a0r[jj] = d8(a0r[jj], a0,a1,a2,a3, *(const uint4*)(lds_u + WH0r + wo));
        a1z[jj] = d8(a1z[jj], a0,a1,a2,a3, *(const uint4*)(lds_u + WX1z + wo));
        a1r[jj] = d8(a1r[jj], a0,a1,a2,a3, *(const uint4*)(lds_u + WX1r + wo));
        a1g[jj] = d8(a1g[jj], a0,a1,a2,a3, *(const uint4*)(lds_u + WX1g + wo));
      }
    }

    // sweep2 over h1: l1 z/r (Wh1) + l2 z/r/g (Wx2)
    #pragma unroll 2
    for (int i = 0; i < 4; ++i) {
      const int ii  = (i + bid) & 3;
      const int kp0 = (w << 5) + (ii << 3) + (ks << 2);
      const unsigned a0 = loadcu(hP1 + (kp0 + 0) * 32 + b);
      const unsigned a1 = loadcu(hP1 + (kp0 + 1) * 32 + b);
      const unsigned a2 = loadcu(hP1 + (kp0 + 2) * 32 + b);
      const unsigned a3 = loadcu(hP1 + (kp0 + 3) * 32 + b);
      #pragma unroll
      for (int jj = 0; jj < 4; ++jj) {
        const int wo = (jj << 9) + kp0;
        a1z[jj] = d8(a1z[jj], a0,a1,a2,a3, *(const uint4*)(lds_u + WH1z + wo));
        a1r[jj] = d8(a1r[jj], a0,a1,a2,a3, *(const uint4*)(lds_u + WH1r + wo));
        a2z[jj] = d8(a2z[jj], a0,a1,a2,a3, *(const uint4*)(lds_u + WX2z + wo));
        a2r[jj] = d8(a2r[jj], a0,a1,a2,a3, *(const uint4*)(lds_u + WX2r + wo));
        a2g[jj] = d8(a2g[jj], a0,a1,a2,a3, *(const uint4*)(lds_u + WX2g + wo));
      }
    }

    // sweep3 over h2: l2 z/r (Wh2) + head (bid<128: Wout row bid)
    #pragma unroll 2
    for (int i = 0; i < 4; ++i) {
      const int ii  = (i + bid) & 3;
      const int kp0 = (w << 5) + (ii << 3) + (ks << 2);
      const unsigned a0 = loadcu(hP2 + (kp0 + 0) * 32 + b);
      const unsigned a1 = loadcu(hP2 + (kp0 + 1) * 32 + b);
      const unsigned a2 = loadcu(hP2 + (kp0 + 2) * 32 + b);
      const unsigned a3 = loadcu(hP2 + (kp0 + 3) * 32 + b);
      #pragma unroll
      for (int jj = 0; jj < 4; ++jj) {
        const int wo = (jj << 9) + kp0;
        a2z[jj] = d8(a2z[jj], a0,a1,a2,a3, *(const uint4*)(lds_u + WH2z + wo));
        a2r[jj] = d8(a2r[jj], a0,a1,a2,a3, *(const uint4*)(lds_u + WH2r + wo));
      }
      if (bid < 128)
        ah = d8(ah, a0,a1,a2,a3, *(const uint4*)(lds_u + WOUTO + kp0));
    }

    // combine ks halves in-wave
    #pragma unroll
    for (int jj = 0; jj < 4; ++jj) {
      a0z[jj] += __shfl_xor(a0z[jj], 32);
      a0r[jj] += __shfl_xor(a0r[jj], 32);
      a0g[jj] += __shfl_xor(a0g[jj], 32);
      a1z[jj] += __shfl_xor(a1z[jj], 32);
      a1r[jj] += __shfl_xor(a1r[jj], 32);
      a1g[jj] += __shfl_xor(a1g[jj], 32);
      a2z[jj] += __shfl_xor(a2z[jj], 32);
      a2r[jj] += __shfl_xor(a2r[jj], 32);
      a2g[jj] += __shfl_xor(a2g[jj], 32);
    }
    ah += __shfl_xor(ah, 32);

    // two-stage fold: upper physical waves deposit, lower add
    if (wPhys >= 8 && ks == 0) {
      #pragma unroll
      for (int jj = 0; jj < 4; ++jj) {
        slot[(0*4+jj)*32 + b] = a0z[jj];
        slot[(1*4+jj)*32 + b] = a0r[jj];
        slot[(2*4+jj)*32 + b] = a0g[jj];
        slot[(3*4+jj)*32 + b] = a1z[jj];
        slot[(4*4+jj)*32 + b] = a1r[jj];
        slot[(5*4+jj)*32 + b] = a1g[jj];
        slot[(6*4+jj)*32 + b] = a2z[jj];
        slot[(7*4+jj)*32 + b] = a2r[jj];
        slot[(8*4+jj)*32 + b] = a2g[jj];
      }
      slot[1152 + b] = ah;
    }
    __syncthreads();
    if (wPhys < 8 && ks == 0) {
      #pragma unroll
      for (int jj = 0; jj < 4; ++jj) {
        slot[(0*4+jj)*32 + b] += a0z[jj];
        slot[(1*4+jj)*32 + b] += a0r[jj];
        slot[(2*4+jj)*32 + b] += a0g[jj];
        slot[(3*4+jj)*32 + b] += a1z[jj];
        slot[(4*4+jj)*32 + b] += a1r[jj];
        slot[(5*4+jj)*32 + b] += a1g[jj];
        slot[(6*4+jj)*32 + b] += a2z[jj];
        slot[(7*4+jj)*32 + b] += a2r[jj];
        slot[(8*4+jj)*32 + b] += a2g[jj];
      }
      slot[1152 + b] += ah;
    }
    __syncthreads();

    // epilogue over 192 threads: wave 0->l0, wave 1->l1, wave 2->l2
    if (tid < 192) {
      const int l   = tid >> 6;          // wave-uniform
      const int sub = tid & 63;
      const int jp  = sub >> 5, bb = sub & 31;
      const int j0  = jbase + (jp << 1);
      float rr0 = 0.f, rr1 = 0.f;
      #pragma unroll
      for (int q = 0; q < 2; ++q) {
        const int jj = (jp << 1) + q;
        float sz = 0.f, sr = 0.f, sg = 0.f;
        #pragma unroll
        for (int ww = 0; ww < 8; ++ww) {
          sz += scratch[ww * 1184 + ((l*3+0)*4 + jj)*32 + bb];
          sr += scratch[ww * 1184 + ((l*3+1)*4 + jj)*32 + bb];
          sg += scratch[ww * 1184 + ((l*3+2)*4 + jj)*32 + bb];
        }
        const int j = j0 + q;
        const float zp = sz + p.bias[l][0][j];
        const float rp = sr + p.bias[l][1][j];
        myGx[q] = sg + p.bias[l][2][j];
        myZ[q]  = 1.f / (1.f + expf(-zp));
        const float r = 1.f / (1.f + expf(-rp));
        const float rrv = r * p.hF[l * 32768 + j * 32 + bb];
        if (q) rr1 = rrv; else rr0 = rrv;
      }
      unsigned* rq = (l == 0) ? rq0 : (l == 1) ? rq1 : rq2;
      storecu(rq + ((bid << 1) + jp) * 32 + bb, pack2(rr0, rr1));
    }
    if (m >= 3 && bid < 128 && tid < 32) {
      float s = 0.f;
      #pragma unroll
      for (int ww = 0; ww < 8; ++ww) s += scratch[ww * 1184 + 1152 + tid];
      p.out[((size_t)tid << 16) + ((size_t)th << 7) + bid] = s + p.bout[bid];
    }

    ++phase; gridbar(p.bar, phase, bid);

    // ===================== phase 2: fused C ===============================
    float c0[4]={0,0,0,0}, c1[4]={0,0,0,0}, c2[4]={0,0,0,0};
    #pragma unroll 2
    for (int i = 0; i < 4; ++i) {
      const int ii  = (i + bid) & 3;
      const int kp0 = (w << 5) + (ii << 3) + (ks << 2);
      const unsigned q00 = loadcu(rq0 + (kp0 + 0) * 32 + b);
      const unsigned q01 = loadcu(rq0 + (kp0 + 1) * 32 + b);
      const unsigned q02 = loadcu(rq0 + (kp0 + 2) * 32 + b);
      const unsigned q03 = loadcu(rq0 + (kp0 + 3) * 32 + b);
      const unsigned q10 = loadcu(rq1 + (kp0 + 0) * 32 + b);
      const unsigned q11 = loadcu(rq1 + (kp0 + 1) * 32 + b);
      const unsigned q12 = loadcu(rq1 + (kp0 + 2) * 32 + b);
      const unsigned q13 = loadcu(rq1 + (kp0 + 3) * 32 + b);
      const unsigned q20 = loadcu(rq2 + (kp0 + 0) * 32 + b);
      const unsigned q21 = loadcu(rq2 + (kp0 + 1) * 32 + b);
      const unsigned q22 = loadcu(rq2 + (kp0 + 2) * 32 + b);
      const unsigned q23 = loadcu(rq2 + (kp0 + 3) * 32 + b);
      #pragma unroll
      for (int jj = 0; jj < 4; ++jj) {
        const int wo = (jj << 9) + kp0;
        c0[jj] = d8(c0[jj], q00,q01,q02,q03, *(const uint4*)(lds_u + WH0g + wo));
        c1[jj] = d8(c1[jj], q10,q11,q12,q13, *(const uint4*)(lds_u + WH1g + wo));
        c2[jj] = d8(c2[jj], q20,q21,q22,q23, *(const uint4*)(lds_u + WH2g + wo));
      }
    }
    #pragma unroll
    for (int jj = 0; jj < 4; ++jj) {
      c0[jj] += __shfl_xor(c0[jj], 32);
      c1[jj] += __shfl_xor(c1[jj], 32);
      c2[jj] += __shfl_xor(c2[jj], 32);
    }
    if (wPhys >= 8 && ks == 0) {
      #pragma unroll
      for (int jj = 0; jj < 4; ++jj) {
        slot[(0*4+jj)*32 + b] = c0[jj];
        slot[(1*4+jj)*32 + b] = c1[jj];
        slot[(2*4+jj)*32 + b] = c2[jj];
      }
    }
    __syncthreads();
    if (wPhys < 8 && ks == 0) {
      #pragma unroll
      for (int jj = 0; jj < 4; ++jj) {
        slot[(0*4+jj)*32 + b] += c0[jj];
        slot[(1*4+jj)*32 + b] += c1[jj];
        slot[(2*4+jj)*32 + b] += c2[jj];
      }
    }
    __syncthreads();
    if (tid < 192) {
      const int l   = tid >> 6;
      const bool act = (l == 0) ? act0 : (l == 1) ? act1 : act2;
      if (act) {
        const int sub = tid & 63;
        const int jp  = sub >> 5, bb = sub & 31;
        const int j0  = jbase + (jp << 1);
        const int tl  = (l == 0) ? t0 : (l == 1) ? t1 : t2;
        float hb0 = 0.f, hb1 = 0.f;
        #pragma unroll
        for (int q = 0; q < 2; ++q) {
          const int jj = (jp << 1) + q;
          float cv = 0.f;
          #pragma unroll
          for (int ww = 0; ww < 8; ++ww)
            cv += scratch[ww * 1184 + (l*4 + jj)*32 + bb];
          const float g = tanhf(cv + myGx[q]);
          float* hf = p.hF + l * 32768 + (j0 + q) * 32 + bb;
          const float hp = *hf;
          const float hn = myZ[q] * hp + (1.f - myZ[q]) * g;
          *hf = hn;
          if (q) hb1 = hn; else hb0 = hn;
          if (tl == 511) p.outHid[bb * 3072 + l * 1024 + (j0 + q)] = hn;
        }
        unsigned* hq = (l == 0) ? hP0 : (l == 1) ? hP1 : hP2;
        storecu(hq + ((bid << 1) + jp) * 32 + bb, pack2(hb0, hb1));
      }
    }
    ++phase; gridbar(p.bar, phase, bid);
  } // m

  // final head: t=511 (16 wave-partials, stride-64 scratch slots)
  float ah = 0.f;
  if (bid < 128) {
    #pragma unroll 2
    for (int i = 0; i < 4; ++i) {
      const int kp0 = (w << 5) + (i << 3) + (ks << 2);
      const unsigned a0 = loadcu(hP2 + (kp0 + 0) * 32 + b);
      const unsigned a1 = loadcu(hP2 + (kp0 + 1) * 32 + b);
      const unsigned a2 = loadcu(hP2 + (kp0 + 2) * 32 + b);
      const unsigned a3 = loadcu(hP2 + (kp0 + 3) * 32 + b);
      ah = d8(ah, a0,a1,a2,a3, *(const uint4*)(lds_u + WOUTO + kp0));
    }
    ah += __shfl_xor(ah, 32);
    if (ks == 0) scratch[wPhys * 64 + b] = ah;
  }
  __syncthreads();
  if (bid < 128 && tid < 32) {
    float s = 0.f;
    #pragma unroll
    for (int ww = 0; ww < 16; ++ww) s += scratch[ww * 64 + tid];
    p.out[((size_t)tid << 16) + ((size_t)511 << 7) + bid] = s + p.bout[bid];
  }
}

// Zero hP, rhP, hF, bar (ws poisoned 0xAA before every timed launch).
__global__ void initWs(unsigned* wsd) {
  const int i = blockIdx.x * 1024 + threadIdx.x;
  if (i < 198656) wsd[i] = 0u;
}

extern "C" void kernel_launch(void* const* d_in, const int* in_sizes, int n_in,
                              void* d_out, int out_size, void* d_ws, size_t ws_size,
                              hipStream_t stream)
{
  GruParams P;
  P.x = (const float*)d_in[0];
  P.Wx[0][0] = (const float*)d_in[1];  P.Wh[0][0] = (const float*)d_in[2];
  P.bias[0][0] = (const float*)d_in[3];
  P.Wx[0][1] = (const float*)d_in[4];  P.Wh[0][1] = (const float*)d_in[5];
  P.bias[0][1] = (const float*)d_in[6];
  P.Wx[0][2] = (const float*)d_in[7];  P.Wh[0][2] = (const float*)d_in[8];
  P.bias[0][2] = (const float*)d_in[9];
  for (int l = 1; l < 3; ++l) {
    const size_t off = (size_t)(l - 1) * 1048576;
    const size_t ob  = (size_t)(l - 1) * 1024;
    P.Wx[l][0] = (const float*)d_in[10] + off; P.Wh[l][0] = (const float*)d_in[11] + off;
    P.bias[l][0] = (const float*)d_in[12] + ob;
    P.Wx[l][1] = (const float*)d_in[13] + off; P.Wh[l][1] = (const float*)d_in[14] + off;
    P.bias[l][1] = (const float*)d_in[15] + ob;
    P.Wx[l][2] = (const float*)d_in[16] + off; P.Wh[l][2] = (const float*)d_in[17] + off;
    P.bias[l][2] = (const float*)d_in[18] + ob;
  }
  P.Wout = (const float*)d_in[19];
  P.bout = (const float*)d_in[20];

  char* ws = (char*)d_ws;
  P.hP  = (unsigned*)ws;                 // 3*16384 uints  = 196,608 B
  P.rhP = (unsigned*)(ws + 196608);      // 3*16384 uints  = 196,608 B
  P.hF  = (float*)(ws + 393216);         // 3*32768 f32    = 393,216 B
  P.bar = (unsigned*)(ws + 786432);      // 2048 uints
  P.out = (float*)d_out;
  P.outHid = P.out + 2097152;

  hipFuncSetAttribute(reinterpret_cast<const void*>(gruPersist),
                      hipFuncAttributeMaxDynamicSharedMemorySize, LDSB);

  initWs<<<194, 1024, 0, stream>>>((unsigned*)ws);
  gruPersist<<<256, 1024, LDSB, stream>>>(P);
}